// Round 5
// baseline (61.565 us; speedup 1.0000x reference)
//
#include <hip/hip_runtime.h>
#include <math.h>
#include <stdint.h>

// GaussianMultiScore: B=524288 independent D=8 Gaussian-product scores.
// R1: per-thread float4 gather: 817MB fetch, 245us.
// R3: LDS-staged cho, 2 full drains/tile: 52us, FETCH=147MB, VALU 13%.
// R4: 1 drain + 2x MLP but waves/CU 10->5: 59us. Latency duty-cycle bound.
// R5: phase-pipelined persistent loop, counted vmcnt(18) waits -> a wave
//     ALWAYS has one 18-load batch in flight; no full drains in the loop.
//     A-side = cho0+mu0 tile, B-side = cho1+mu1 tile (18KB each).
//
// Math (one Cholesky total): lam_new = cho0+cho1 = M.
//  Mt = J*M*J = Gt*Gt^T;  diag(chol(inv(M))) = reversed 1/diag(Gt)
//  sum(log diag_new^2) = -logdet(M);  mu_new via two triangular solves;
//  diff^T M diff = ||Gt^T (J diff)||^2;  det_sum(faithful) = sum 1/gt_ii^2.

constexpr float LOG_2PI_F = 1.8378770664093453f;
constexpr double TWO_PI_D = 6.283185307179586476925286766559;
constexpr float POW8_2PI =
    (float)(TWO_PI_D*TWO_PI_D*TWO_PI_D*TWO_PI_D*TWO_PI_D*TWO_PI_D*TWO_PI_D*TWO_PI_D);

#define TRI(i) (((i)*((i)+1))/2)

typedef __attribute__((address_space(1))) const uint32_t glb_u32_t;
typedef __attribute__((address_space(3))) uint32_t       lds_u32_t;

// 16 gload_lds: 64 elements x 256B of cho, XOR-swizzled via the SOURCE addr
// (global_load_lds writes linearly, base + lane*16).
__device__ __forceinline__ void stage_cho(const float* __restrict__ choP,
                                          size_t blockBase, int B,
                                          float* buf, int t)
{
#pragma unroll
    for (int i = 0; i < 16; ++i) {
        int g  = i * 64 + t;        // linear f4 slot in the 1024-f4 tile
        int r  = g >> 4;            // local element 0..63
        int s4 = g & 15;            // f4 slot within element
        int j  = s4 ^ (r & 15);     // logical f4 index whose data lands here
        size_t e = blockBase + (size_t)r;
        if (e >= (size_t)B) e = (size_t)B - 1;
        __builtin_amdgcn_global_load_lds(
            (glb_u32_t*)(const void*)(choP + e * 64 + (size_t)(j * 4)),
            (lds_u32_t*)(void*)(buf + g * 4),
            16, 0, 0);
    }
}

// 2 gload_lds: 64 elements x 32B of mu, linear (coalesced both sides).
__device__ __forceinline__ void stage_mu(const float* __restrict__ muP,
                                         size_t blockBase, float* buf, int t)
{
#pragma unroll
    for (int i = 0; i < 2; ++i) {
        int off = i * 256 + t * 4;          // floats within the 512-float tile
        __builtin_amdgcn_global_load_lds(
            (glb_u32_t*)(const void*)(muP + blockBase * 8 + (size_t)off),
            (lds_u32_t*)(void*)(buf + off),
            16, 0, 0);
    }
}

#define WAIT_VM(N) asm volatile("s_waitcnt vmcnt(" #N ")" ::: "memory")

template <bool FIRST>
__device__ __forceinline__ void pass_lds(
    const float* cbuf, const float* mbuf, int t,
    float mt[36], float eta[8], float& quad_out, float& prod_out)
{
    float mu[8];
    {
        const float4* M4 = reinterpret_cast<const float4*>(mbuf);
        float4 a = M4[2 * t], c = M4[2 * t + 1];   // 4-way bank conflict, 2 reads: ok
        mu[0]=a.x; mu[1]=a.y; mu[2]=a.z; mu[3]=a.w;
        mu[4]=c.x; mu[5]=c.y; mu[6]=c.z; mu[7]=c.w;
    }
    const float4* L4 = reinterpret_cast<const float4*>(cbuf);
    const int base = t * 16;
    const int sw   = t & 15;
    float quad = 0.0f, prod = 1.0f;
#pragma unroll
    for (int r = 0; r < 8; ++r) {
        float4 lo = L4[base + ((2 * r)     ^ sw)];
        float4 hi = L4[base + ((2 * r + 1) ^ sw)];
        float row[8] = {lo.x, lo.y, lo.z, lo.w, hi.x, hi.y, hi.z, hi.w};
        float e = 0.0f;
#pragma unroll
        for (int j = 0; j < 8; ++j) e = fmaf(row[j], mu[j], e);
        if (FIRST) eta[r] = e; else eta[r] += e;
        quad = fmaf(mu[r], e, quad);
        prod *= row[r];
        // reversed lower triangle: Mt[i][j] = M[7-i][7-j], keep j<=i (c>=r)
#pragma unroll
        for (int c = r; c < 8; ++c) {
            int i = 7 - r, jj = 7 - c;
            if (FIRST) mt[TRI(i) + jj]  = row[c];
            else       mt[TRI(i) + jj] += row[c];
        }
    }
    quad_out = quad;
    prod_out = prod;
}

__global__ __launch_bounds__(64) void gms_kernel(
    const float* __restrict__ mu0, const float* __restrict__ mu1,
    const float* __restrict__ cho0, const float* __restrict__ cho1,
    const float* __restrict__ sample, float* __restrict__ out, int B)
{
    __shared__ float Ac[64 * 64];   // cho0 tile (16KB)
    __shared__ float Bc[64 * 64];   // cho1 tile (16KB)
    __shared__ float Am[64 * 8];    // mu0 tile (2KB)
    __shared__ float Bm[64 * 8];    // mu1 tile (2KB)   -> 36KB/block

    const int t = threadIdx.x;
    const int nTiles = B >> 6;
    int tile = blockIdx.x;
    const int stride = gridDim.x;
    if (tile >= nTiles) return;

    float s[8];
    {
        float4 v0 = reinterpret_cast<const float4*>(sample)[0];
        float4 v1 = reinterpret_cast<const float4*>(sample)[1];
        s[0]=v0.x; s[1]=v0.y; s[2]=v0.z; s[3]=v0.w;
        s[4]=v1.x; s[5]=v1.y; s[6]=v1.z; s[7]=v1.w;
    }

    // Prologue: A-side batch (18 loads) for the first tile.
    stage_cho(cho0, (size_t)tile * 64, B, Ac, t);
    stage_mu (mu0,  (size_t)tile * 64,    Am, t);

    while (tile < nTiles) {
        const size_t blockBase = (size_t)tile * 64;
        const size_t bb = blockBase + (size_t)t;

        // B-side batch (18 loads) for THIS tile.
        stage_cho(cho1, blockBase, B, Bc, t);
        stage_mu (mu1,  blockBase,    Bm, t);

        // Wait for A-side (everything older than the 18 just issued).
        WAIT_VM(18);

        float mt[36], eta[8];
        float quad0, quad1, p0, p1;
        pass_lds<true>(Ac, Am, t, mt, eta, quad0, p0);

        // A-side batch (18 loads) for the NEXT tile, in flight over pass1+epilogue.
        const int next = tile + stride;
        if (next < nTiles) {
            stage_cho(cho0, (size_t)next * 64, B, Ac, t);
            stage_mu (mu0,  (size_t)next * 64,    Am, t);
            WAIT_VM(18);    // B-side done; next A-side stays outstanding
        } else {
            WAIT_VM(0);     // tail: drain B-side
        }

        pass_lds<false>(Bc, Bm, t, mt, eta, quad1, p1);

        // ---- Cholesky of mt in place (D=8, fully unrolled) ----
        float ginv[8];
        float gprod = 1.0f;
#pragma unroll
        for (int j = 0; j < 8; ++j) {
            float d = mt[TRI(j) + j];
#pragma unroll
            for (int k = 0; k < j; ++k) {
                float v = mt[TRI(j) + k];
                d = fmaf(-v, v, d);
            }
            float sq = sqrtf(d);
            mt[TRI(j) + j] = sq;
            gprod *= sq;
            float inv = 1.0f / sq;
            ginv[j] = inv;
#pragma unroll
            for (int i = j + 1; i < 8; ++i) {
                float v = mt[TRI(i) + j];
#pragma unroll
                for (int k = 0; k < j; ++k)
                    v = fmaf(-mt[TRI(i) + k], mt[TRI(j) + k], v);
                mt[TRI(i) + j] = v * inv;
            }
        }
        float logdetM = __logf(gprod * gprod);

        // ---- solve Mt * xt = reversed(eta) ----
        float er[8];
#pragma unroll
        for (int i = 0; i < 8; ++i) er[i] = eta[7 - i];
        float y[8];
#pragma unroll
        for (int i = 0; i < 8; ++i) {
            float v = er[i];
#pragma unroll
            for (int k = 0; k < i; ++k) v = fmaf(-mt[TRI(i) + k], y[k], v);
            y[i] = v * ginv[i];
        }
        float x[8];
#pragma unroll
        for (int ii = 7; ii >= 0; --ii) {
            float v = y[ii];
#pragma unroll
            for (int k = ii + 1; k < 8; ++k) v = fmaf(-mt[TRI(k) + ii], x[k], v);
            x[ii] = v * ginv[ii];
        }

        float qn = 0.0f;
#pragma unroll
        for (int i = 0; i < 8; ++i) qn = fmaf(x[i], er[i], qn);

        float dd[8];
#pragma unroll
        for (int i = 0; i < 8; ++i) dd[i] = x[i] - s[7 - i];
        float ep = 0.0f;
#pragma unroll
        for (int i = 0; i < 8; ++i) {
            float z = 0.0f;
#pragma unroll
            for (int k = i; k < 8; ++k) z = fmaf(mt[TRI(k) + i], dd[k], z);
            ep = fmaf(z, z, ep);
        }
        float exp_part = -0.5f * ep;

        float det_sum = 0.0f;
#pragma unroll
        for (int i = 0; i < 8; ++i) det_sum = fmaf(ginv[i], ginv[i], det_sum);

        float sumlog0 = __logf(p0 * p0);
        float sumlog1 = __logf(p1 * p1);
        float zeta0   = -0.5f * (8.0f * LOG_2PI_F - sumlog0 + quad0);
        float zeta1   = -0.5f * (8.0f * LOG_2PI_F - sumlog1 + quad1);
        float zeta_n  = -0.5f * (8.0f * LOG_2PI_F + logdetM + qn);
        float scale   = zeta0 + zeta1 - zeta_n;

        float result = __expf(scale + exp_part) / sqrtf(POW8_2PI * det_sum);
        if (bb < (size_t)B) out[bb] = result;

        tile = next;
    }
}

extern "C" void kernel_launch(void* const* d_in, const int* in_sizes, int n_in,
                              void* d_out, int out_size, void* d_ws, size_t ws_size,
                              hipStream_t stream) {
    const float* mu0    = (const float*)d_in[0];
    const float* mu1    = (const float*)d_in[1];
    const float* cho0   = (const float*)d_in[2];
    const float* cho1   = (const float*)d_in[3];
    const float* sample = (const float*)d_in[4];
    float* out = (float*)d_out;
    int B = in_sizes[0] / 8;
    int nTiles = (B + 63) / 64;
    int blocks = nTiles < 1280 ? nTiles : 1280;   // 5 blocks/CU at 36KB LDS... (160/36=4; HW rounds LDS, 4-5/CU)
    gms_kernel<<<dim3(blocks), dim3(64), 0, stream>>>(
        mu0, mu1, cho0, cho1, sample, out, B);
}